// Round 1
// baseline (527.699 us; speedup 1.0000x reference)
//
#include <hip/hip_runtime.h>

// ---- problem constants ----
#define L_DIM 197
#define N_DIM 256
#define C_DIM 768
#define CA_DIM 192
#define M_DIM (L_DIM * N_DIM)   // 50432
#define T_FR 16

typedef short s16x8 __attribute__((ext_vector_type(8)));
typedef float f32x4 __attribute__((ext_vector_type(4)));

__device__ __forceinline__ unsigned short f2bf(float f) {
  unsigned x = __builtin_bit_cast(unsigned, f);
  x = (x + 0x7fffu + ((x >> 16) & 1u)) >> 16;   // RNE
  return (unsigned short)x;
}
__device__ __forceinline__ float bflo(unsigned u) { return __builtin_bit_cast(float, u << 16); }
__device__ __forceinline__ float bfhi(unsigned u) { return __builtin_bit_cast(float, u & 0xffff0000u); }

__device__ __forceinline__ void unp8(uint4 v, float* f) {
  f[0] = bflo(v.x); f[1] = bfhi(v.x); f[2] = bflo(v.y); f[3] = bfhi(v.y);
  f[4] = bflo(v.z); f[5] = bfhi(v.z); f[6] = bflo(v.w); f[7] = bfhi(v.w);
}

__device__ __forceinline__ void mfma16(f32x4& acc, s16x8 a, s16x8 b) {
  // D = A(16x32) * B(32x16) + D, bf16 inputs, fp32 acc. Inline asm avoids the
  // builtin operand-type (bf16x8 vs short8) ambiguity; register deps visible
  // to the hazard recognizer.
  asm("v_mfma_f32_16x16x32_bf16 %0, %1, %2, %0" : "+v"(acc) : "v"(a), "v"(b));
}

// ---------------------------------------------------------------------------
// prep: transpose + fp32->bf16 all six weight matrices.
// wa[n][k] (576 x 768): n = [fc1 | mlp_in | off_fc1] output-channel, k = C.
// wc[n][k] (768 x 576): n = C out, k = [h2(fc2) | m1(mlp_out) | off2(off_fc2)].
// ---------------------------------------------------------------------------
__global__ __launch_bounds__(256) void prep_k(
    const float* __restrict__ fc1_w, const float* __restrict__ mlp_in_w,
    const float* __restrict__ off_fc1_w, const float* __restrict__ fc2_w,
    const float* __restrict__ mlp_out_w, const float* __restrict__ off_fc2_w,
    unsigned short* __restrict__ wa, unsigned short* __restrict__ wc) {
  const int idx = blockIdx.x * 256 + threadIdx.x;   // [0, 2*576*768)
  if (idx < 576 * 768) {
    const int n = idx / 768, k = idx - (idx / 768) * 768;
    const int sel = n / 192, ca = n - sel * 192;
    const float* w = sel == 0 ? fc1_w : (sel == 1 ? mlp_in_w : off_fc1_w);
    wa[idx] = f2bf(w[k * 192 + ca]);                // w is (C, CA) row-major
  } else {
    const int i2 = idx - 576 * 768;
    const int n = i2 / 576, k = i2 - (i2 / 576) * 576;
    const int sel = k / 192, kl = k - sel * 192;
    const float* w = sel == 0 ? fc2_w : (sel == 1 ? mlp_out_w : off_fc2_w);
    wc[i2] = f2bf(w[kl * 768 + n]);                 // w is (CA, C) row-major
  }
}

// ---------------------------------------------------------------------------
// gemm_a: Y = x(50432x768 fp32) @ wa^T-block. BM=128, BN=192 (= one path per
// blockIdx.x), BK=32, 512 threads = 8 waves (2m x 4n), per-wave 64x48.
// Epilogue: path 0 -> h1 (+fc1_b), path 1 -> m1 (gelu(+mlp_in_b)), path 2 -> yoff.
// ---------------------------------------------------------------------------
__global__ __launch_bounds__(512, 1) void gemm_a_k(
    const float* __restrict__ x, const unsigned short* __restrict__ wt,
    const float* __restrict__ fc1_b, const float* __restrict__ mlp_in_b,
    unsigned short* __restrict__ h1, unsigned short* __restrict__ m1o,
    unsigned short* __restrict__ yoff) {
  __shared__ unsigned short As[2][128 * 32];
  __shared__ unsigned short Bs[2][192 * 32];
  const int tid = threadIdx.x;
  const int lane = tid & 63, wid = tid >> 6;
  const int bx = blockIdx.x;          // path 0..2
  const int by = blockIdx.y;          // m-tile 0..393
  const int m0 = by * 128;
  const int n0 = bx * 192;

  const int arow = tid >> 3, ac4 = tid & 7;     // A: 2 float4/thread (rows +0,+64)
  const float* ab_ = x + (m0 + arow) * C_DIM + ac4 * 4;
  const unsigned short* bb_ = wt + (n0 + arow) * C_DIM + ac4 * 4;  // B: 3 uint2/thread

  float4 ar[2];
  uint2 br[3];
  auto ld = [&](int kt) {
    const float* p = ab_ + kt * 32;
    ar[0] = *(const float4*)(p);
    ar[1] = *(const float4*)(p + 64 * C_DIM);
    const unsigned short* q = bb_ + kt * 32;
    br[0] = *(const uint2*)(q);
    br[1] = *(const uint2*)(q + 64 * C_DIM);
    br[2] = *(const uint2*)(q + 128 * C_DIM);
  };
  auto st = [&](int b) {
#pragma unroll
    for (int i = 0; i < 2; i++) {
      ushort4 v;
      v.x = f2bf(ar[i].x); v.y = f2bf(ar[i].y); v.z = f2bf(ar[i].z); v.w = f2bf(ar[i].w);
      *(ushort4*)&As[b][(arow + i * 64) * 32 + ac4 * 4] = v;
    }
#pragma unroll
    for (int i = 0; i < 3; i++)
      *(uint2*)&Bs[b][(arow + i * 64) * 32 + ac4 * 4] = br[i];
  };

  f32x4 acc[4][3];
#pragma unroll
  for (int a2 = 0; a2 < 4; a2++)
#pragma unroll
    for (int b2 = 0; b2 < 3; b2++) acc[a2][b2] = (f32x4){0.f, 0.f, 0.f, 0.f};

  const int fr = lane & 15, fq = lane >> 4;
  const int wm = (wid >> 2) * 64, wn = (wid & 3) * 48;

  ld(0); st(0); ld(1);
#pragma unroll 2
  for (int kt = 0; kt < 24; ++kt) {
    __syncthreads();
    if (kt + 1 < 24) {
      st((kt + 1) & 1);
      if (kt + 2 < 24) ld(kt + 2);
    }
    const int b = kt & 1;
    s16x8 af[4], bf_[3];
#pragma unroll
    for (int mi = 0; mi < 4; mi++)
      af[mi] = *(const s16x8*)&As[b][(wm + mi * 16 + fr) * 32 + fq * 8];
#pragma unroll
    for (int ni = 0; ni < 3; ni++)
      bf_[ni] = *(const s16x8*)&Bs[b][(wn + ni * 16 + fr) * 32 + fq * 8];
#pragma unroll
    for (int mi = 0; mi < 4; mi++)
#pragma unroll
      for (int ni = 0; ni < 3; ni++) mfma16(acc[mi][ni], af[mi], bf_[ni]);
  }

  unsigned short* dst = bx == 0 ? h1 : (bx == 1 ? m1o : yoff);
#pragma unroll
  for (int ni = 0; ni < 3; ni++) {
    const int ca = wn + ni * 16 + fr;
    const float bv = bx == 0 ? fc1_b[ca] : (bx == 1 ? mlp_in_b[ca] : 0.f);
#pragma unroll
    for (int mi = 0; mi < 4; mi++)
#pragma unroll
      for (int r = 0; r < 4; r++) {
        const int m = m0 + wm + mi * 16 + fq * 4 + r;
        float v = acc[mi][ni][r] + bv;
        if (bx == 1) v = v / (1.f + __expf(-1.702f * v));   // quick_gelu
        dst[m * CA_DIM + ca] = f2bf(v);
      }
  }
}

// ---------------------------------------------------------------------------
// conv1d: depthwise conv over t (n%16) with zero padding. h1 -> h2 (+conv_b).
// one thread per (m, 8 channels).
// ---------------------------------------------------------------------------
__global__ __launch_bounds__(256) void conv1d_k(
    const unsigned short* __restrict__ h1, const float* __restrict__ cw,
    const float* __restrict__ cb, unsigned short* __restrict__ h2) {
  const int idx = blockIdx.x * 256 + threadIdx.x;   // exactly 50432*24
  const int m = idx / 24;
  const int c8 = idx - m * 24;
  const int t = m & 15;
  const int ca0 = c8 * 8;
  const int base = m * CA_DIM + ca0;
  uint4 z; z.x = z.y = z.z = z.w = 0u;
  const uint4 cu = *(const uint4*)(h1 + base);
  const uint4 pu = (t > 0) ? *(const uint4*)(h1 + base - CA_DIM) : z;
  const uint4 nu = (t < 15) ? *(const uint4*)(h1 + base + CA_DIM) : z;
  float pf[8], cf[8], nf[8];
  unp8(pu, pf); unp8(cu, cf); unp8(nu, nf);
  unsigned o[4];
#pragma unroll
  for (int e = 0; e < 8; e += 2) {
    const float r0 = cw[(ca0 + e) * 3] * pf[e] + cw[(ca0 + e) * 3 + 1] * cf[e] +
                     cw[(ca0 + e) * 3 + 2] * nf[e] + cb[ca0 + e];
    const float r1 = cw[(ca0 + e + 1) * 3] * pf[e + 1] + cw[(ca0 + e + 1) * 3 + 1] * cf[e + 1] +
                     cw[(ca0 + e + 1) * 3 + 2] * nf[e + 1] + cb[ca0 + e + 1];
    o[e / 2] = (unsigned)f2bf(r0) | ((unsigned)f2bf(r1) << 16);
  }
  uint4 ov; ov.x = o[0]; ov.y = o[1]; ov.z = o[2]; ov.w = o[3];
  *(uint4*)(h2 + base) = ov;
}

// ---------------------------------------------------------------------------
// conv3d: offset branch. d(b,t,hw,ca) = (t>0 ? y[t]-y[t-1] : 0) + off_fc1_b,
// then 3x3 spatial depthwise conv (zero pad) + off_conv_b -> off2 rows l>=1.
// one thread per (hw, n, 8 channels).
// ---------------------------------------------------------------------------
__global__ __launch_bounds__(256) void conv3d_k(
    const unsigned short* __restrict__ y, const float* __restrict__ b1,
    const float* __restrict__ w3, const float* __restrict__ b2,
    unsigned short* __restrict__ off2) {
  const int idx = blockIdx.x * 256 + threadIdx.x;   // exactly 196*256*24
  const int c8 = idx % 24;
  const int tmp = idx / 24;
  const int n = tmp & 255;
  const int hw = tmp >> 8;            // 0..195
  const int i = hw / 14, j = hw - i * 14;
  const int t = n & 15;
  const int ca0 = c8 * 8;
  float b1v[8], acc[8];
#pragma unroll
  for (int e = 0; e < 8; e++) { b1v[e] = b1[ca0 + e]; acc[e] = b2[ca0 + e]; }
#pragma unroll
  for (int di = 0; di < 3; ++di) {
    const int ii = i + di - 1;
    if (ii < 0 || ii >= 14) continue;
#pragma unroll
    for (int dj = 0; dj < 3; ++dj) {
      const int jj = j + dj - 1;
      if (jj < 0 || jj >= 14) continue;
      const int rbase = ((1 + ii * 14 + jj) * N_DIM + n) * CA_DIM + ca0;
      float a0[8], a1[8];
      unp8(*(const uint4*)(y + rbase), a0);
      if (t > 0) unp8(*(const uint4*)(y + rbase - CA_DIM), a1);
#pragma unroll
      for (int e = 0; e < 8; e++) {
        const float d = ((t > 0) ? (a0[e] - a1[e]) : 0.f) + b1v[e];
        acc[e] += w3[(ca0 + e) * 9 + di * 3 + dj] * d;
      }
    }
  }
  const int obase = ((1 + hw) * N_DIM + n) * CA_DIM + ca0;
  unsigned o[4];
#pragma unroll
  for (int e = 0; e < 8; e += 2)
    o[e / 2] = (unsigned)f2bf(acc[e]) | ((unsigned)f2bf(acc[e + 1]) << 16);
  uint4 ov; ov.x = o[0]; ov.y = o[1]; ov.z = o[2]; ov.w = o[3];
  *(uint4*)(off2 + obase) = ov;
}

// ---------------------------------------------------------------------------
// gemm_c: out = [h2|m1|off2](50432x576) @ wc^T + biases. BM=128, BN=128,
// BK=32, 256 threads = 4 waves (2x2), per-wave 64x64. off_fc2_b gated on l>0
// (uniform: l = by/2; off2 row block l=0 is zeroed so its GEMM term vanishes).
// ---------------------------------------------------------------------------
__global__ __launch_bounds__(256, 1) void gemm_c_k(
    const unsigned short* __restrict__ h2, const unsigned short* __restrict__ m1o,
    const unsigned short* __restrict__ off2, const unsigned short* __restrict__ wt,
    const float* __restrict__ fc2_b, const float* __restrict__ mlp_out_b,
    const float* __restrict__ off_fc2_b, float* __restrict__ out) {
  __shared__ unsigned short As[2][128 * 32];
  __shared__ unsigned short Bs[2][128 * 32];
  const int tid = threadIdx.x;
  const int lane = tid & 63, wid = tid >> 6;
  const int bx = blockIdx.x, by = blockIdx.y;
  const int m0 = by * 128, n0 = bx * 128;
  const int arow = tid >> 2, ac8 = tid & 3;     // 2 uint4/thread (rows +0,+64)

  uint4 ar[2], br[2];
  auto ld = [&](int kt) {
    const unsigned short* base = kt < 6 ? h2 : (kt < 12 ? m1o : off2);
    const int kl = (kt - (kt < 6 ? 0 : (kt < 12 ? 6 : 12))) * 32;
    const unsigned short* p = base + (m0 + arow) * CA_DIM + kl + ac8 * 8;
    ar[0] = *(const uint4*)(p);
    ar[1] = *(const uint4*)(p + 64 * CA_DIM);
    const unsigned short* q = wt + (n0 + arow) * 576 + kt * 32 + ac8 * 8;
    br[0] = *(const uint4*)(q);
    br[1] = *(const uint4*)(q + 64 * 576);
  };
  auto st = [&](int b) {
    *(uint4*)&As[b][arow * 32 + ac8 * 8] = ar[0];
    *(uint4*)&As[b][(arow + 64) * 32 + ac8 * 8] = ar[1];
    *(uint4*)&Bs[b][arow * 32 + ac8 * 8] = br[0];
    *(uint4*)&Bs[b][(arow + 64) * 32 + ac8 * 8] = br[1];
  };

  f32x4 acc[4][4];
#pragma unroll
  for (int a2 = 0; a2 < 4; a2++)
#pragma unroll
    for (int b2 = 0; b2 < 4; b2++) acc[a2][b2] = (f32x4){0.f, 0.f, 0.f, 0.f};

  const int fr = lane & 15, fq = lane >> 4;
  const int wm = (wid >> 1) * 64, wn = (wid & 1) * 64;

  ld(0); st(0); ld(1);
#pragma unroll 2
  for (int kt = 0; kt < 18; ++kt) {
    __syncthreads();
    if (kt + 1 < 18) {
      st((kt + 1) & 1);
      if (kt + 2 < 18) ld(kt + 2);
    }
    const int b = kt & 1;
    s16x8 af[4], bf_[4];
#pragma unroll
    for (int mi = 0; mi < 4; mi++)
      af[mi] = *(const s16x8*)&As[b][(wm + mi * 16 + fr) * 32 + fq * 8];
#pragma unroll
    for (int ni = 0; ni < 4; ni++)
      bf_[ni] = *(const s16x8*)&Bs[b][(wn + ni * 16 + fr) * 32 + fq * 8];
#pragma unroll
    for (int mi = 0; mi < 4; mi++)
#pragma unroll
      for (int ni = 0; ni < 4; ni++) mfma16(acc[mi][ni], af[mi], bf_[ni]);
  }

  float bv[4];
#pragma unroll
  for (int ni = 0; ni < 4; ni++) {
    const int c = n0 + wn + ni * 16 + fr;
    bv[ni] = fc2_b[c] + mlp_out_b[c] + (by >= 2 ? off_fc2_b[c] : 0.f);
  }
#pragma unroll
  for (int mi = 0; mi < 4; mi++)
#pragma unroll
    for (int r = 0; r < 4; r++) {
      const int m = m0 + wm + mi * 16 + fq * 4 + r;
      float* op = out + m * C_DIM + n0 + wn;
#pragma unroll
      for (int ni = 0; ni < 4; ni++) op[ni * 16 + fr] = acc[mi][ni][r] + bv[ni];
    }
}

// ---------------------------------------------------------------------------
extern "C" void kernel_launch(void* const* d_in, const int* in_sizes, int n_in,
                              void* d_out, int out_size, void* d_ws, size_t ws_size,
                              hipStream_t stream) {
  const float* x          = (const float*)d_in[0];
  // d_in[1] = T (unused, hardcoded 16)
  const float* fc1_w      = (const float*)d_in[2];
  const float* fc1_b      = (const float*)d_in[3];
  const float* conv_w     = (const float*)d_in[4];
  const float* conv_b     = (const float*)d_in[5];
  const float* fc2_w      = (const float*)d_in[6];
  const float* fc2_b      = (const float*)d_in[7];
  const float* off_fc1_w  = (const float*)d_in[8];
  const float* off_fc1_b  = (const float*)d_in[9];
  const float* off_conv_w = (const float*)d_in[10];
  const float* off_conv_b = (const float*)d_in[11];
  const float* off_fc2_w  = (const float*)d_in[12];
  const float* off_fc2_b  = (const float*)d_in[13];
  const float* mlp_in_w   = (const float*)d_in[14];
  const float* mlp_in_b   = (const float*)d_in[15];
  const float* mlp_out_w  = (const float*)d_in[16];
  const float* mlp_out_b  = (const float*)d_in[17];
  float* out = (float*)d_out;

  char* ws = (char*)d_ws;
  const size_t IB = (size_t)M_DIM * CA_DIM * 2;   // 19,365,888 B per intermediate
  unsigned short* h1   = (unsigned short*)(ws + 0 * IB);
  unsigned short* m1   = (unsigned short*)(ws + 1 * IB);
  unsigned short* yoff = (unsigned short*)(ws + 2 * IB);
  unsigned short* h2   = (unsigned short*)(ws + 3 * IB);
  unsigned short* off2 = (unsigned short*)(ws + 4 * IB);
  unsigned short* wa   = (unsigned short*)(ws + 5 * IB);
  unsigned short* wc   = (unsigned short*)(ws + 5 * IB + (size_t)576 * 768 * 2);

  prep_k<<<3456, 256, 0, stream>>>(fc1_w, mlp_in_w, off_fc1_w, fc2_w, mlp_out_w,
                                   off_fc2_w, wa, wc);
  gemm_a_k<<<dim3(3, 394), 512, 0, stream>>>(x, wa, fc1_b, mlp_in_b, h1, m1, yoff);
  conv1d_k<<<4728, 256, 0, stream>>>(h1, conv_w, conv_b, h2);
  conv3d_k<<<4704, 256, 0, stream>>>(yoff, off_fc1_b, off_conv_w, off_conv_b, off2);
  hipMemsetAsync(off2, 0, (size_t)N_DIM * CA_DIM * 2, stream);   // off2 rows l=0 -> 0
  gemm_c_k<<<dim3(6, 394), 256, 0, stream>>>(h2, m1, off2, wc, fc2_b, mlp_out_b,
                                             off_fc2_b, out);
}

// Round 2
// 344.129 us; speedup vs baseline: 1.5334x; 1.5334x over previous
//
#include <hip/hip_runtime.h>

// ---- problem constants ----
#define L_DIM 197
#define N_DIM 256
#define C_DIM 768
#define CA_DIM 192
#define M_DIM (L_DIM * N_DIM)   // 50432

typedef short s16x8 __attribute__((ext_vector_type(8)));
typedef float f32x4 __attribute__((ext_vector_type(4)));

__device__ __forceinline__ unsigned short f2bf(float f) {
  unsigned x = __builtin_bit_cast(unsigned, f);
  x = (x + 0x7fffu + ((x >> 16) & 1u)) >> 16;   // RNE
  return (unsigned short)x;
}
__device__ __forceinline__ float bflo(unsigned u) { return __builtin_bit_cast(float, u << 16); }
__device__ __forceinline__ float bfhi(unsigned u) { return __builtin_bit_cast(float, u & 0xffff0000u); }

__device__ __forceinline__ void unp8(uint4 v, float* f) {
  f[0] = bflo(v.x); f[1] = bfhi(v.x); f[2] = bflo(v.y); f[3] = bfhi(v.y);
  f[4] = bflo(v.z); f[5] = bfhi(v.z); f[6] = bflo(v.w); f[7] = bfhi(v.w);
}

__device__ __forceinline__ void mfma16(f32x4& acc, s16x8 a, s16x8 b) {
  asm("v_mfma_f32_16x16x32_bf16 %0, %1, %2, %0" : "+v"(acc) : "v"(a), "v"(b));
}

// async global->LDS 16B (wave-uniform LDS base + lane*16 — our layouts are linear)
typedef const void __attribute__((address_space(1)))* gp_t;
typedef void __attribute__((address_space(3)))* lp_t;
__device__ __forceinline__ void gl16(const void* g, void* l) {
  __builtin_amdgcn_global_load_lds((gp_t)g, (lp_t)l, 16, 0, 0);
}

// bijective XCD-chunk swizzle (m204): physical pid -> logical id such that each
// XCD (pid%8) owns a contiguous logical range; bx-inner => A-panel sharers co-XCD.
__device__ __forceinline__ int swz(int pid, int nwg) {
  const int q = nwg >> 3, r = nwg & 7, x = pid & 7, s = pid >> 3;
  return (x < r ? x * (q + 1) : r * (q + 1) + (x - r) * q) + s;
}

// ---------------------------------------------------------------------------
// prep: LDS-tiled transpose + fp32->bf16 of all six weight matrices.
// wa[576][768]: rows = [fc1|mlp_in|off_fc1] out-channel, cols = C (k).
// wc[768][576]: rows = C out, cols = [fc2|mlp_out|off_fc2] (k).
// ---------------------------------------------------------------------------
__global__ __launch_bounds__(256) void prep_k(
    const float* __restrict__ fc1_w, const float* __restrict__ mlp_in_w,
    const float* __restrict__ off_fc1_w, const float* __restrict__ fc2_w,
    const float* __restrict__ mlp_out_w, const float* __restrict__ off_fc2_w,
    unsigned short* __restrict__ wa, unsigned short* __restrict__ wc) {
  __shared__ float t[32][33];
  const int b = blockIdx.x;              // 0..863
  const int job = b / 144, tt = b - job * 144;
  const float* in = job == 0 ? fc1_w : job == 1 ? mlp_in_w : job == 2 ? off_fc1_w
                  : job == 3 ? fc2_w : job == 4 ? mlp_out_w : off_fc2_w;
  const int Cc = job < 3 ? 192 : 768;    // input col count (input is rows x Cc)
  const int tc = Cc >> 5;
  const int tr0 = (tt / tc) << 5, tc0 = (tt - (tt / tc) * tc) << 5;
  const int lr = threadIdx.x >> 5, lc = threadIdx.x & 31;
#pragma unroll
  for (int p = 0; p < 4; p++)
    t[p * 8 + lr][lc] = in[(tr0 + p * 8 + lr) * Cc + tc0 + lc];
  __syncthreads();
#pragma unroll
  for (int p = 0; p < 4; p++) {
    const int orow = tc0 + p * 8 + lr;   // = input col
    const int ocol = tr0 + lc;           // = input row
    const unsigned short v = f2bf(t[lc][p * 8 + lr]);
    if (job < 3) wa[(job * 192 + orow) * 768 + ocol] = v;
    else         wc[orow * 576 + (job - 3) * 192 + ocol] = v;
  }
}

// ---------------------------------------------------------------------------
// gemm_a: Y = x(50432x768 fp32) @ wa-panel^T. BM=128, BN=192 (bx = path),
// BK=32, 256 threads = 4 waves (2m x 2n), per-wave 64x96 (24 MFMA/K-step).
// A: reg-staged fp32->bf16 (loads issued one K-step early); B: global_load_lds.
// Epilogue: bx0 -> h1(+fc1_b), bx1 -> hcat[.,192:384] (gelu(+mlp_in_b)),
// bx2 -> yoff (no bias).
// ---------------------------------------------------------------------------
__global__ __launch_bounds__(256, 1) void gemm_a_k(
    const float* __restrict__ x, const unsigned short* __restrict__ wa,
    const float* __restrict__ fc1_b, const float* __restrict__ mlp_in_b,
    unsigned short* __restrict__ h1, unsigned short* __restrict__ hcat,
    unsigned short* __restrict__ yoff) {
  __shared__ unsigned short As[2][128 * 32];
  __shared__ unsigned short Bs[2][192 * 32];
  const int tid = threadIdx.x, lane = tid & 63, w = tid >> 6;
  const int lid = swz(blockIdx.x, 3 * 394);
  const int by = lid / 3, bx = lid - by * 3;
  const int m0 = by * 128, n0 = bx * 192;

  // A: thread handles rows {ar, ar+64}, 8 consecutive fp32 at col ac
  const int ar = tid >> 2, ac = (tid & 3) << 3;
  const float* ga = x + (m0 + ar) * C_DIM + ac;
  // B: per-wave 3 gload_lds instrs; linear LDS rows
  const int brow = w * 48 + (lane >> 2), bc = (lane & 3) << 3;
  const unsigned short* gb = wa + (n0 + brow) * C_DIM + bc;

  float4 av[4];
  auto ldA = [&](int kt) {
    const float* p = ga + kt * 32;
    av[0] = *(const float4*)p;                 av[1] = *(const float4*)(p + 4);
    av[2] = *(const float4*)(p + 64 * C_DIM);  av[3] = *(const float4*)(p + 64 * C_DIM + 4);
  };
  auto wrA = [&](int b) {
#pragma unroll
    for (int i = 0; i < 2; i++) {
      s16x8 v;
      const float4 u0 = av[2 * i], u1 = av[2 * i + 1];
      v[0] = (short)f2bf(u0.x); v[1] = (short)f2bf(u0.y);
      v[2] = (short)f2bf(u0.z); v[3] = (short)f2bf(u0.w);
      v[4] = (short)f2bf(u1.x); v[5] = (short)f2bf(u1.y);
      v[6] = (short)f2bf(u1.z); v[7] = (short)f2bf(u1.w);
      *(s16x8*)&As[b][(ar + i * 64) * 32 + ac] = v;
    }
  };
  auto stB = [&](int kt, int b) {
#pragma unroll
    for (int j = 0; j < 3; j++)
      gl16(gb + kt * 32 + j * 16 * C_DIM, &Bs[b][(brow + j * 16) * 32 + bc]);
  };

  f32x4 acc[4][6];
#pragma unroll
  for (int i = 0; i < 4; i++)
#pragma unroll
    for (int j = 0; j < 6; j++) acc[i][j] = (f32x4){0.f, 0.f, 0.f, 0.f};

  const int fr = lane & 15, fq = lane >> 4;
  const int wm = (w >> 1) * 64, wn = (w & 1) * 96;

  ldA(0); stB(0, 0); wrA(0); ldA(1);
  __syncthreads();
#pragma unroll 2
  for (int kt = 0; kt < 24; ++kt) {
    const int b = kt & 1;
    if (kt + 1 < 24) {
      stB(kt + 1, b ^ 1);
      wrA(b ^ 1);
      if (kt + 2 < 24) ldA(kt + 2);
    }
    s16x8 af[4], bfv[6];
#pragma unroll
    for (int mi = 0; mi < 4; mi++)
      af[mi] = *(const s16x8*)&As[b][(wm + mi * 16 + fr) * 32 + fq * 8];
#pragma unroll
    for (int ni = 0; ni < 6; ni++)
      bfv[ni] = *(const s16x8*)&Bs[b][(wn + ni * 16 + fr) * 32 + fq * 8];
#pragma unroll
    for (int mi = 0; mi < 4; mi++)
#pragma unroll
      for (int ni = 0; ni < 6; ni++) mfma16(acc[mi][ni], af[mi], bfv[ni]);
    __syncthreads();
  }

  unsigned short* dst; int stride;
  if (bx == 0)      { dst = h1;            stride = CA_DIM; }
  else if (bx == 1) { dst = hcat + CA_DIM; stride = 576; }
  else              { dst = yoff;          stride = CA_DIM; }
#pragma unroll
  for (int ni = 0; ni < 6; ni++) {
    const int ca = wn + ni * 16 + fr;
    const float bv = bx == 0 ? fc1_b[ca] : (bx == 1 ? mlp_in_b[ca] : 0.f);
#pragma unroll
    for (int mi = 0; mi < 4; mi++)
#pragma unroll
      for (int r = 0; r < 4; r++) {
        const int m = m0 + wm + mi * 16 + fq * 4 + r;
        float v = acc[mi][ni][r] + bv;
        if (bx == 1) v = v / (1.f + __expf(-1.702f * v));   // quick_gelu
        dst[m * stride + ca] = f2bf(v);
      }
  }
}

// ---------------------------------------------------------------------------
// conv1d: depthwise conv over t (m%16), h1 -> hcat cols [0,192) (+conv_b).
// ---------------------------------------------------------------------------
__global__ __launch_bounds__(256) void conv1d_k(
    const unsigned short* __restrict__ h1, const float* __restrict__ cw,
    const float* __restrict__ cb, unsigned short* __restrict__ hcat) {
  const int idx = blockIdx.x * 256 + threadIdx.x;   // 50432*24
  const int m = idx / 24;
  const int c8 = idx - m * 24;
  const int t = m & 15;
  const int ca0 = c8 * 8;
  const int base = m * CA_DIM + ca0;
  uint4 z; z.x = z.y = z.z = z.w = 0u;
  const uint4 cu = *(const uint4*)(h1 + base);
  const uint4 pu = (t > 0) ? *(const uint4*)(h1 + base - CA_DIM) : z;
  const uint4 nu = (t < 15) ? *(const uint4*)(h1 + base + CA_DIM) : z;
  float pf[8], cf[8], nf[8];
  unp8(pu, pf); unp8(cu, cf); unp8(nu, nf);
  unsigned o[4];
#pragma unroll
  for (int e = 0; e < 8; e += 2) {
    const float r0 = cw[(ca0 + e) * 3] * pf[e] + cw[(ca0 + e) * 3 + 1] * cf[e] +
                     cw[(ca0 + e) * 3 + 2] * nf[e] + cb[ca0 + e];
    const float r1 = cw[(ca0 + e + 1) * 3] * pf[e + 1] + cw[(ca0 + e + 1) * 3 + 1] * cf[e + 1] +
                     cw[(ca0 + e + 1) * 3 + 2] * nf[e + 1] + cb[ca0 + e + 1];
    o[e / 2] = (unsigned)f2bf(r0) | ((unsigned)f2bf(r1) << 16);
  }
  uint4 ov; ov.x = o[0]; ov.y = o[1]; ov.z = o[2]; ov.w = o[3];
  *(uint4*)(hcat + m * 576 + ca0) = ov;
}

// ---------------------------------------------------------------------------
// conv3d: offset branch -> hcat cols [384,576), rows l>=1.
// ---------------------------------------------------------------------------
__global__ __launch_bounds__(256) void conv3d_k(
    const unsigned short* __restrict__ y, const float* __restrict__ b1,
    const float* __restrict__ w3, const float* __restrict__ b2,
    unsigned short* __restrict__ hcat) {
  const int idx = blockIdx.x * 256 + threadIdx.x;   // 196*256*24
  const int c8 = idx % 24;
  const int tmp = idx / 24;
  const int n = tmp & 255;
  const int hw = tmp >> 8;            // 0..195
  const int i = hw / 14, j = hw - i * 14;
  const int t = n & 15;
  const int ca0 = c8 * 8;
  float b1v[8], acc[8];
#pragma unroll
  for (int e = 0; e < 8; e++) { b1v[e] = b1[ca0 + e]; acc[e] = b2[ca0 + e]; }
#pragma unroll
  for (int di = 0; di < 3; ++di) {
    const int ii = i + di - 1;
    if (ii < 0 || ii >= 14) continue;
#pragma unroll
    for (int dj = 0; dj < 3; ++dj) {
      const int jj = j + dj - 1;
      if (jj < 0 || jj >= 14) continue;
      const int rbase = ((1 + ii * 14 + jj) * N_DIM + n) * CA_DIM + ca0;
      float a0[8], a1[8];
      unp8(*(const uint4*)(y + rbase), a0);
      if (t > 0) unp8(*(const uint4*)(y + rbase - CA_DIM), a1);
#pragma unroll
      for (int e = 0; e < 8; e++) {
        const float d = ((t > 0) ? (a0[e] - a1[e]) : 0.f) + b1v[e];
        acc[e] += w3[(ca0 + e) * 9 + di * 3 + dj] * d;
      }
    }
  }
  const int orow = (1 + hw) * N_DIM + n;
  unsigned o[4];
#pragma unroll
  for (int e = 0; e < 8; e += 2)
    o[e / 2] = (unsigned)f2bf(acc[e]) | ((unsigned)f2bf(acc[e + 1]) << 16);
  uint4 ov; ov.x = o[0]; ov.y = o[1]; ov.z = o[2]; ov.w = o[3];
  *(uint4*)(hcat + orow * 576 + 384 + ca0) = ov;
}

// zero-fill hcat rows l=0 (m<256), cols [384,576)
__global__ __launch_bounds__(256) void zfill_k(unsigned short* __restrict__ hcat) {
  const int idx = blockIdx.x * 256 + threadIdx.x;   // 256*24
  const int m = idx / 24, ch = idx - (idx / 24) * 24;
  s16x8 z = (s16x8){0, 0, 0, 0, 0, 0, 0, 0};
  *(s16x8*)&hcat[m * 576 + 384 + ch * 8] = z;
}

// ---------------------------------------------------------------------------
// gemm_c: out = hcat(50432x576) @ wc^T + biases. BM=128, BN=128, BK=32,
// 256 threads = 4 waves (2x2), per-wave 64x64. Both operands via
// global_load_lds (m97 structure), double-buffered, 1 barrier/K-step.
// ---------------------------------------------------------------------------
__global__ __launch_bounds__(256, 1) void gemm_c_k(
    const unsigned short* __restrict__ hcat, const unsigned short* __restrict__ wc,
    const float* __restrict__ fc2_b, const float* __restrict__ mlp_out_b,
    const float* __restrict__ off_fc2_b, float* __restrict__ out) {
  __shared__ unsigned short As[2][128 * 32];
  __shared__ unsigned short Bs[2][128 * 32];
  const int tid = threadIdx.x, lane = tid & 63, w = tid >> 6;
  const int lid = swz(blockIdx.x, 6 * 394);
  const int by = lid / 6, bx = lid - by * 6;
  const int m0 = by * 128, n0 = bx * 128;

  const int srow = w * 32 + (lane >> 2), sc = (lane & 3) << 3;
  const unsigned short* gA = hcat + (m0 + srow) * 576 + sc;
  const unsigned short* gB = wc + (n0 + srow) * 576 + sc;
  auto stage = [&](int kt, int b) {
#pragma unroll
    for (int j = 0; j < 2; j++) {
      gl16(gA + kt * 32 + j * 16 * 576, &As[b][(srow + j * 16) * 32 + sc]);
      gl16(gB + kt * 32 + j * 16 * 576, &Bs[b][(srow + j * 16) * 32 + sc]);
    }
  };

  f32x4 acc[4][4];
#pragma unroll
  for (int i = 0; i < 4; i++)
#pragma unroll
    for (int j = 0; j < 4; j++) acc[i][j] = (f32x4){0.f, 0.f, 0.f, 0.f};

  const int fr = lane & 15, fq = lane >> 4;
  const int wm = (w >> 1) * 64, wn = (w & 1) * 64;

  stage(0, 0);
  __syncthreads();
#pragma unroll 2
  for (int kt = 0; kt < 18; ++kt) {
    const int b = kt & 1;
    if (kt + 1 < 18) stage(kt + 1, b ^ 1);
    s16x8 af[4], bfv[4];
#pragma unroll
    for (int mi = 0; mi < 4; mi++)
      af[mi] = *(const s16x8*)&As[b][(wm + mi * 16 + fr) * 32 + fq * 8];
#pragma unroll
    for (int ni = 0; ni < 4; ni++)
      bfv[ni] = *(const s16x8*)&Bs[b][(wn + ni * 16 + fr) * 32 + fq * 8];
#pragma unroll
    for (int mi = 0; mi < 4; mi++)
#pragma unroll
      for (int ni = 0; ni < 4; ni++) mfma16(acc[mi][ni], af[mi], bfv[ni]);
    __syncthreads();
  }

  float bv[4];
#pragma unroll
  for (int ni = 0; ni < 4; ni++) {
    const int c = n0 + wn + ni * 16 + fr;
    bv[ni] = fc2_b[c] + mlp_out_b[c] + (by >= 2 ? off_fc2_b[c] : 0.f);
  }
#pragma unroll
  for (int mi = 0; mi < 4; mi++)
#pragma unroll
    for (int r = 0; r < 4; r++) {
      const int m = m0 + wm + mi * 16 + fq * 4 + r;
      float* op = out + m * C_DIM + n0 + wn;
#pragma unroll
      for (int ni = 0; ni < 4; ni++) op[ni * 16 + fr] = acc[mi][ni][r] + bv[ni];
    }
}

// ---------------------------------------------------------------------------
extern "C" void kernel_launch(void* const* d_in, const int* in_sizes, int n_in,
                              void* d_out, int out_size, void* d_ws, size_t ws_size,
                              hipStream_t stream) {
  const float* x          = (const float*)d_in[0];
  const float* fc1_w      = (const float*)d_in[2];
  const float* fc1_b      = (const float*)d_in[3];
  const float* conv_w     = (const float*)d_in[4];
  const float* conv_b     = (const float*)d_in[5];
  const float* fc2_w      = (const float*)d_in[6];
  const float* fc2_b      = (const float*)d_in[7];
  const float* off_fc1_w  = (const float*)d_in[8];
  const float* off_fc1_b  = (const float*)d_in[9];
  const float* off_conv_w = (const float*)d_in[10];
  const float* off_conv_b = (const float*)d_in[11];
  const float* off_fc2_w  = (const float*)d_in[12];
  const float* off_fc2_b  = (const float*)d_in[13];
  const float* mlp_in_w   = (const float*)d_in[14];
  const float* mlp_in_b   = (const float*)d_in[15];
  const float* mlp_out_w  = (const float*)d_in[16];
  const float* mlp_out_b  = (const float*)d_in[17];
  float* out = (float*)d_out;

  char* ws = (char*)d_ws;
  const size_t IB = (size_t)M_DIM * CA_DIM * 2;       // 19.4 MB
  unsigned short* h1   = (unsigned short*)(ws);
  unsigned short* yoff = (unsigned short*)(ws + IB);
  unsigned short* hcat = (unsigned short*)(ws + 2 * IB);          // [M][576]
  unsigned short* wa   = (unsigned short*)(ws + 2 * IB + (size_t)M_DIM * 576 * 2);
  unsigned short* wc   = wa + (size_t)576 * 768;

  prep_k<<<864, 256, 0, stream>>>(fc1_w, mlp_in_w, off_fc1_w, fc2_w, mlp_out_w,
                                  off_fc2_w, wa, wc);
  gemm_a_k<<<1182, 256, 0, stream>>>(x, wa, fc1_b, mlp_in_b, h1, hcat, yoff);
  conv1d_k<<<4728, 256, 0, stream>>>(h1, conv_w, conv_b, hcat);
  conv3d_k<<<4704, 256, 0, stream>>>(yoff, off_fc1_b, off_conv_w, off_conv_b, hcat);
  zfill_k<<<24, 256, 0, stream>>>(hcat);
  gemm_c_k<<<2364, 256, 0, stream>>>(hcat, wc, fc2_b, mlp_out_b, off_fc2_b, out);
}

// Round 4
// 212.798 us; speedup vs baseline: 2.4798x; 1.6172x over previous
//
#include <hip/hip_runtime.h>

// ---- problem constants ----
#define L_DIM 197
#define N_DIM 256
#define C_DIM 768
#define CA_DIM 192
#define M_DIM (L_DIM * N_DIM)   // 50432

typedef short s16x8 __attribute__((ext_vector_type(8)));
typedef float f32x4 __attribute__((ext_vector_type(4)));

__device__ __forceinline__ unsigned short f2bf(float f) {
  unsigned x = __builtin_bit_cast(unsigned, f);
  x = (x + 0x7fffu + ((x >> 16) & 1u)) >> 16;   // RNE
  return (unsigned short)x;
}
__device__ __forceinline__ float bflo(unsigned u) { return __builtin_bit_cast(float, u << 16); }
__device__ __forceinline__ float bfhi(unsigned u) { return __builtin_bit_cast(float, u & 0xffff0000u); }

__device__ __forceinline__ void unp8(uint4 v, float* f) {
  f[0] = bflo(v.x); f[1] = bfhi(v.x); f[2] = bflo(v.y); f[3] = bfhi(v.y);
  f[4] = bflo(v.z); f[5] = bfhi(v.z); f[6] = bflo(v.w); f[7] = bfhi(v.w);
}

__device__ __forceinline__ void mfma16(f32x4& acc, s16x8 a, s16x8 b) {
  asm("v_mfma_f32_16x16x32_bf16 %0, %1, %2, %0" : "+v"(acc) : "v"(a), "v"(b));
}

// async global->LDS 16B (wave-uniform LDS base + lane*16 — our layouts are linear)
typedef const void __attribute__((address_space(1)))* gp_t;
typedef void __attribute__((address_space(3)))* lp_t;
__device__ __forceinline__ void gl16(const void* g, void* l) {
  __builtin_amdgcn_global_load_lds((gp_t)g, (lp_t)l, 16, 0, 0);
}

// bijective XCD-chunk swizzle (m204)
__device__ __forceinline__ int swz(int pid, int nwg) {
  const int q = nwg >> 3, r = nwg & 7, x = pid & 7, s = pid >> 3;
  return (x < r ? x * (q + 1) : r * (q + 1) + (x - r) * q) + s;
}

// ---------------------------------------------------------------------------
// prep: LDS-tiled transpose + fp32->bf16 of all six weight matrices.
// ---------------------------------------------------------------------------
__global__ __launch_bounds__(256) void prep_k(
    const float* __restrict__ fc1_w, const float* __restrict__ mlp_in_w,
    const float* __restrict__ off_fc1_w, const float* __restrict__ fc2_w,
    const float* __restrict__ mlp_out_w, const float* __restrict__ off_fc2_w,
    unsigned short* __restrict__ wa, unsigned short* __restrict__ wc) {
  __shared__ float t[32][33];
  const int b = blockIdx.x;              // 0..863
  const int job = b / 144, tt = b - job * 144;
  const float* in = job == 0 ? fc1_w : job == 1 ? mlp_in_w : job == 2 ? off_fc1_w
                  : job == 3 ? fc2_w : job == 4 ? mlp_out_w : off_fc2_w;
  const int Cc = job < 3 ? 192 : 768;
  const int tc = Cc >> 5;
  const int tr0 = (tt / tc) << 5, tc0 = (tt - (tt / tc) * tc) << 5;
  const int lr = threadIdx.x >> 5, lc = threadIdx.x & 31;
#pragma unroll
  for (int p = 0; p < 4; p++)
    t[p * 8 + lr][lc] = in[(tr0 + p * 8 + lr) * Cc + tc0 + lc];
  __syncthreads();
#pragma unroll
  for (int p = 0; p < 4; p++) {
    const int orow = tc0 + p * 8 + lr;
    const int ocol = tr0 + lc;
    const unsigned short v = f2bf(t[lc][p * 8 + lr]);
    if (job < 3) wa[(job * 192 + orow) * 768 + ocol] = v;
    else         wc[orow * 576 + (job - 3) * 192 + ocol] = v;
  }
}

// ---------------------------------------------------------------------------
// gemm_a: BM=128, BN=192 (bx = path), BK=32, 4 waves, per-wave 64x96.
// ---------------------------------------------------------------------------
__global__ __launch_bounds__(256, 1) void gemm_a_k(
    const float* __restrict__ x, const unsigned short* __restrict__ wa,
    const float* __restrict__ fc1_b, const float* __restrict__ mlp_in_b,
    unsigned short* __restrict__ h1, unsigned short* __restrict__ hcat,
    unsigned short* __restrict__ yoff) {
  __shared__ unsigned short As[2][128 * 32];
  __shared__ unsigned short Bs[2][192 * 32];
  const int tid = threadIdx.x, lane = tid & 63, w = tid >> 6;
  const int lid = swz(blockIdx.x, 3 * 394);
  const int by = lid / 3, bx = lid - by * 3;
  const int m0 = by * 128, n0 = bx * 192;

  const int ar = tid >> 2, ac = (tid & 3) << 3;
  const float* ga = x + (m0 + ar) * C_DIM + ac;
  const int brow = w * 48 + (lane >> 2), bc = (lane & 3) << 3;
  const unsigned short* gb = wa + (n0 + brow) * C_DIM + bc;

  float4 av[4];
  auto ldA = [&](int kt) {
    const float* p = ga + kt * 32;
    av[0] = *(const float4*)p;                 av[1] = *(const float4*)(p + 4);
    av[2] = *(const float4*)(p + 64 * C_DIM);  av[3] = *(const float4*)(p + 64 * C_DIM + 4);
  };
  auto wrA = [&](int b) {
#pragma unroll
    for (int i = 0; i < 2; i++) {
      s16x8 v;
      const float4 u0 = av[2 * i], u1 = av[2 * i + 1];
      v[0] = (short)f2bf(u0.x); v[1] = (short)f2bf(u0.y);
      v[2] = (short)f2bf(u0.z); v[3] = (short)f2bf(u0.w);
      v[4] = (short)f2bf(u1.x); v[5] = (short)f2bf(u1.y);
      v[6] = (short)f2bf(u1.z); v[7] = (short)f2bf(u1.w);
      *(s16x8*)&As[b][(ar + i * 64) * 32 + ac] = v;
    }
  };
  auto stB = [&](int kt, int b) {
#pragma unroll
    for (int j = 0; j < 3; j++)
      gl16(gb + kt * 32 + j * 16 * C_DIM, &Bs[b][(brow + j * 16) * 32 + bc]);
  };

  f32x4 acc[4][6];
#pragma unroll
  for (int i = 0; i < 4; i++)
#pragma unroll
    for (int j = 0; j < 6; j++) acc[i][j] = (f32x4){0.f, 0.f, 0.f, 0.f};

  const int fr = lane & 15, fq = lane >> 4;
  const int wm = (w >> 1) * 64, wn = (w & 1) * 96;

  ldA(0); stB(0, 0); wrA(0); ldA(1);
  __syncthreads();
#pragma unroll 2
  for (int kt = 0; kt < 24; ++kt) {
    const int b = kt & 1;
    if (kt + 1 < 24) {
      stB(kt + 1, b ^ 1);
      wrA(b ^ 1);
      if (kt + 2 < 24) ldA(kt + 2);
    }
    s16x8 af[4], bfv[6];
#pragma unroll
    for (int mi = 0; mi < 4; mi++)
      af[mi] = *(const s16x8*)&As[b][(wm + mi * 16 + fr) * 32 + fq * 8];
#pragma unroll
    for (int ni = 0; ni < 6; ni++)
      bfv[ni] = *(const s16x8*)&Bs[b][(wn + ni * 16 + fr) * 32 + fq * 8];
#pragma unroll
    for (int mi = 0; mi < 4; mi++)
#pragma unroll
      for (int ni = 0; ni < 6; ni++) mfma16(acc[mi][ni], af[mi], bfv[ni]);
    __syncthreads();
  }

  unsigned short* dst; int stride;
  if (bx == 0)      { dst = h1;            stride = CA_DIM; }
  else if (bx == 1) { dst = hcat + CA_DIM; stride = 576; }
  else              { dst = yoff;          stride = CA_DIM; }
#pragma unroll
  for (int ni = 0; ni < 6; ni++) {
    const int ca = wn + ni * 16 + fr;
    const float bv = bx == 0 ? fc1_b[ca] : (bx == 1 ? mlp_in_b[ca] : 0.f);
#pragma unroll
    for (int mi = 0; mi < 4; mi++)
#pragma unroll
      for (int r = 0; r < 4; r++) {
        const int m = m0 + wm + mi * 16 + fq * 4 + r;
        float v = acc[mi][ni][r] + bv;
        if (bx == 1) v = v / (1.f + __expf(-1.702f * v));   // quick_gelu
        dst[m * stride + ca] = f2bf(v);
      }
  }
}

// ---------------------------------------------------------------------------
// conv1d: 8 items/thread, channel chunk invariant -> weights in registers.
// ---------------------------------------------------------------------------
__global__ __launch_bounds__(256) void conv1d_k(
    const unsigned short* __restrict__ h1, const float* __restrict__ cw,
    const float* __restrict__ cb, unsigned short* __restrict__ hcat) {
  const int t0 = blockIdx.x * 256 + threadIdx.x;   // 591*256 = 151,296 threads
  const int c8 = t0 % 24;                          // stride 151296 % 24 == 0
  const int ca0 = c8 * 8;
  float w0[8], w1[8], w2[8], bb[8];
#pragma unroll
  for (int e = 0; e < 8; e++) {
    w0[e] = cw[(ca0 + e) * 3 + 0];
    w1[e] = cw[(ca0 + e) * 3 + 1];
    w2[e] = cw[(ca0 + e) * 3 + 2];
    bb[e] = cb[ca0 + e];
  }
  int m = t0 / 24;
#pragma unroll
  for (int k = 0; k < 8; k++, m += 6304) {
    const int t = m & 15;
    const int base = m * CA_DIM + ca0;
    uint4 z; z.x = z.y = z.z = z.w = 0u;
    const uint4 cu = *(const uint4*)(h1 + base);
    const uint4 pu = (t > 0) ? *(const uint4*)(h1 + base - CA_DIM) : z;
    const uint4 nu = (t < 15) ? *(const uint4*)(h1 + base + CA_DIM) : z;
    float pf[8], cf[8], nf[8];
    unp8(pu, pf); unp8(cu, cf); unp8(nu, nf);
    unsigned o[4];
#pragma unroll
    for (int e = 0; e < 8; e += 2) {
      const float r0 = w0[e] * pf[e] + w1[e] * cf[e] + w2[e] * nf[e] + bb[e];
      const float r1 = w0[e+1] * pf[e+1] + w1[e+1] * cf[e+1] + w2[e+1] * nf[e+1] + bb[e+1];
      o[e / 2] = (unsigned)f2bf(r0) | ((unsigned)f2bf(r1) << 16);
    }
    uint4 ov; ov.x = o[0]; ov.y = o[1]; ov.z = o[2]; ov.w = o[3];
    *(uint4*)(hcat + (size_t)m * 576 + ca0) = ov;
  }
}

// ---------------------------------------------------------------------------
// conv3d v2: one block per (frame n, channel quarter q). Stage
// d = (t>0 ? y[n]-y[n-1] : 0) + b1 as fp32 in LDS; 3x3 taps read from LDS.
// ---------------------------------------------------------------------------
__global__ __launch_bounds__(256) void conv3d_k(
    const unsigned short* __restrict__ y, const float* __restrict__ b1,
    const float* __restrict__ w3, const float* __restrict__ b2,
    unsigned short* __restrict__ hcat) {
  __shared__ float ds[196 * 48];
  __shared__ float w3s[9 * 48];
  __shared__ float b2s[48];
  const int blk = blockIdx.x;           // 1024 = 256 frames x 4 quarters
  const int n = blk >> 2, q = blk & 3;
  const int t = n & 15;
  const int ch0 = q * 48;
  const int tid = threadIdx.x;

  for (int j = tid; j < 432; j += 256) {          // FIX: block has 256 threads
    const int c = j / 9, tap = j % 9;
    w3s[tap * 48 + c] = w3[(ch0 + c) * 9 + tap];
  }
  if (tid < 48) b2s[tid] = b2[ch0 + tid];

  for (int j = tid; j < 196 * 6; j += 256) {
    const int hw = j / 6, ck = j % 6;
    const int ca = ch0 + ck * 8;
    float dv[8];
    if (t > 0) {
      const unsigned short* p = y + ((size_t)(1 + hw) * 256 + n) * 192 + ca;
      float a0[8], a1[8];
      unp8(*(const uint4*)p, a0);
      unp8(*(const uint4*)(p - 192), a1);
#pragma unroll
      for (int e = 0; e < 8; e++) dv[e] = a0[e] - a1[e] + b1[ca + e];
    } else {
#pragma unroll
      for (int e = 0; e < 8; e++) dv[e] = b1[ca + e];
    }
#pragma unroll
    for (int e = 0; e < 8; e++) ds[hw * 48 + ck * 8 + e] = dv[e];
  }
  __syncthreads();

  for (int j = tid; j < 196 * 6; j += 256) {
    const int hw = j / 6, ck = j % 6;
    const int i = hw / 14, j0 = hw - i * 14;
    float acc[8];
#pragma unroll
    for (int e = 0; e < 8; e++) acc[e] = b2s[ck * 8 + e];
#pragma unroll
    for (int di = 0; di < 3; di++) {
      const int ii = i + di - 1;
      if (ii < 0 || ii >= 14) continue;
#pragma unroll
      for (int dj = 0; dj < 3; dj++) {
        const int jc = j0 + dj - 1;
        if (jc < 0 || jc >= 14) continue;
        const float* dp = &ds[(ii * 14 + jc) * 48 + ck * 8];
        const float* wp = &w3s[(di * 3 + dj) * 48 + ck * 8];
#pragma unroll
        for (int e = 0; e < 8; e++) acc[e] += wp[e] * dp[e];
      }
    }
    unsigned o[4];
#pragma unroll
    for (int e = 0; e < 8; e += 2)
      o[e / 2] = (unsigned)f2bf(acc[e]) | ((unsigned)f2bf(acc[e + 1]) << 16);
    uint4 ov; ov.x = o[0]; ov.y = o[1]; ov.z = o[2]; ov.w = o[3];
    *(uint4*)(hcat + ((size_t)(1 + hw) * 256 + n) * 576 + 384 + ch0 + ck * 8) = ov;
  }
}

// zero-fill hcat rows l=0 (m<256), cols [384,576)
__global__ __launch_bounds__(256) void zfill_k(unsigned short* __restrict__ hcat) {
  const int idx = blockIdx.x * 256 + threadIdx.x;   // 256*24
  const int m = idx / 24, ch = idx - (idx / 24) * 24;
  s16x8 z = (s16x8){0, 0, 0, 0, 0, 0, 0, 0};
  *(s16x8*)&hcat[m * 576 + 384 + ch * 8] = z;
}

// ---------------------------------------------------------------------------
// gemm_c: out = hcat(50432x576) @ wc^T + biases. m97 structure.
// ---------------------------------------------------------------------------
__global__ __launch_bounds__(256, 1) void gemm_c_k(
    const unsigned short* __restrict__ hcat, const unsigned short* __restrict__ wc,
    const float* __restrict__ fc2_b, const float* __restrict__ mlp_out_b,
    const float* __restrict__ off_fc2_b, float* __restrict__ out) {
  __shared__ unsigned short As[2][128 * 32];
  __shared__ unsigned short Bs[2][128 * 32];
  const int tid = threadIdx.x, lane = tid & 63, w = tid >> 6;
  const int lid = swz(blockIdx.x, 6 * 394);
  const int by = lid / 6, bx = lid - by * 6;
  const int m0 = by * 128, n0 = bx * 128;

  const int srow = w * 32 + (lane >> 2), sc = (lane & 3) << 3;
  const unsigned short* gA = hcat + (m0 + srow) * 576 + sc;
  const unsigned short* gB = wc + (n0 + srow) * 576 + sc;
  auto stage = [&](int kt, int b) {
#pragma unroll
    for (int j = 0; j < 2; j++) {
      gl16(gA + kt * 32 + j * 16 * 576, &As[b][(srow + j * 16) * 32 + sc]);
      gl16(gB + kt * 32 + j * 16 * 576, &Bs[b][(srow + j * 16) * 32 + sc]);
    }
  };

  f32x4 acc[4][4];
#pragma unroll
  for (int i = 0; i < 4; i++)
#pragma unroll
    for (int j = 0; j < 4; j++) acc[i][j] = (f32x4){0.f, 0.f, 0.f, 0.f};

  const int fr = lane & 15, fq = lane >> 4;
  const int wm = (w >> 1) * 64, wn = (w & 1) * 64;

  stage(0, 0);
  __syncthreads();
#pragma unroll 2
  for (int kt = 0; kt < 18; ++kt) {
    const int b = kt & 1;
    if (kt + 1 < 18) stage(kt + 1, b ^ 1);
    s16x8 af[4], bfv[4];
#pragma unroll
    for (int mi = 0; mi < 4; mi++)
      af[mi] = *(const s16x8*)&As[b][(wm + mi * 16 + fr) * 32 + fq * 8];
#pragma unroll
    for (int ni = 0; ni < 4; ni++)
      bfv[ni] = *(const s16x8*)&Bs[b][(wn + ni * 16 + fr) * 32 + fq * 8];
#pragma unroll
    for (int mi = 0; mi < 4; mi++)
#pragma unroll
      for (int ni = 0; ni < 4; ni++) mfma16(acc[mi][ni], af[mi], bfv[ni]);
    __syncthreads();
  }

  float bv[4];
#pragma unroll
  for (int ni = 0; ni < 4; ni++) {
    const int c = n0 + wn + ni * 16 + fr;
    bv[ni] = fc2_b[c] + mlp_out_b[c] + (by >= 2 ? off_fc2_b[c] : 0.f);
  }
#pragma unroll
  for (int mi = 0; mi < 4; mi++)
#pragma unroll
    for (int r = 0; r < 4; r++) {
      const int m = m0 + wm + mi * 16 + fq * 4 + r;
      float* op = out + m * C_DIM + n0 + wn;
#pragma unroll
      for (int ni = 0; ni < 4; ni++) op[ni * 16 + fr] = acc[mi][ni][r] + bv[ni];
    }
}

// ---------------------------------------------------------------------------
extern "C" void kernel_launch(void* const* d_in, const int* in_sizes, int n_in,
                              void* d_out, int out_size, void* d_ws, size_t ws_size,
                              hipStream_t stream) {
  const float* x          = (const float*)d_in[0];
  const float* fc1_w      = (const float*)d_in[2];
  const float* fc1_b      = (const float*)d_in[3];
  const float* conv_w     = (const float*)d_in[4];
  const float* conv_b     = (const float*)d_in[5];
  const float* fc2_w      = (const float*)d_in[6];
  const float* fc2_b      = (const float*)d_in[7];
  const float* off_fc1_w  = (const float*)d_in[8];
  const float* off_fc1_b  = (const float*)d_in[9];
  const float* off_conv_w = (const float*)d_in[10];
  const float* off_conv_b = (const float*)d_in[11];
  const float* off_fc2_w  = (const float*)d_in[12];
  const float* off_fc2_b  = (const float*)d_in[13];
  const float* mlp_in_w   = (const float*)d_in[14];
  const float* mlp_in_b   = (const float*)d_in[15];
  const float* mlp_out_w  = (const float*)d_in[16];
  const float* mlp_out_b  = (const float*)d_in[17];
  float* out = (float*)d_out;

  char* ws = (char*)d_ws;
  const size_t IB = (size_t)M_DIM * CA_DIM * 2;       // 19.4 MB
  unsigned short* h1   = (unsigned short*)(ws);
  unsigned short* yoff = (unsigned short*)(ws + IB);
  unsigned short* hcat = (unsigned short*)(ws + 2 * IB);          // [M][576]
  unsigned short* wa   = (unsigned short*)(ws + 2 * IB + (size_t)M_DIM * 576 * 2);
  unsigned short* wc   = wa + (size_t)576 * 768;

  prep_k<<<864, 256, 0, stream>>>(fc1_w, mlp_in_w, off_fc1_w, fc2_w, mlp_out_w,
                                  off_fc2_w, wa, wc);
  gemm_a_k<<<1182, 256, 0, stream>>>(x, wa, fc1_b, mlp_in_b, h1, hcat, yoff);
  conv1d_k<<<591, 256, 0, stream>>>(h1, conv_w, conv_b, hcat);
  conv3d_k<<<1024, 256, 0, stream>>>(yoff, off_fc1_b, off_conv_w, off_conv_b, hcat);
  zfill_k<<<24, 256, 0, stream>>>(hcat);
  gemm_c_k<<<2364, 256, 0, stream>>>(hcat, wc, fc2_b, mlp_out_b, off_fc2_b, out);
}